// Round 1
// baseline (397.885 us; speedup 1.0000x reference)
//
#include <hip/hip_runtime.h>

// Problem constants
#define D_DIM 1024
#define L_DIM 4096
#define B_DIM 4
#define M_DIM (B_DIM * L_DIM)   // 16384 rows
#define N1    3072              // concat of K1|Q1|K2 outputs
#define CHUNKS 64
#define LC     64               // chunk length (CHUNKS*LC == L_DIM)

using f32x4  = __attribute__((ext_vector_type(4))) float;
using bf16x8 = __attribute__((ext_vector_type(8))) short;

__device__ __forceinline__ unsigned short f2bf(float f) {
    unsigned u = __float_as_uint(f);
    u += 0x7fffu + ((u >> 16) & 1u);   // RNE
    return (unsigned short)(u >> 16);
}
__device__ __forceinline__ float bf2f(unsigned short h) {
    return __uint_as_float(((unsigned)h) << 16);
}
__device__ __forceinline__ float sigmoidf_(float x) {
    return 1.0f / (1.0f + __expf(-x));
}

// fp32 -> bf16 conversion, 4 elems/thread (all sizes divisible by 4)
__global__ void cvt_bf16_kernel(const float* __restrict__ in, unsigned short* __restrict__ out, int n) {
    int i = (blockIdx.x * blockDim.x + threadIdx.x) * 4;
    if (i < n) {
        float4 v = *reinterpret_cast<const float4*>(in + i);
        uint2 p;
        p.x = (unsigned)f2bf(v.x) | ((unsigned)f2bf(v.y) << 16);
        p.y = (unsigned)f2bf(v.z) | ((unsigned)f2bf(v.w) << 16);
        *reinterpret_cast<uint2*>(out + i) = p;
    }
}

__device__ __forceinline__ void gld_lds16(const void* g, void* s) {
    __builtin_amdgcn_global_load_lds((const __attribute__((address_space(1))) void*)g,
                                     (__attribute__((address_space(3))) void*)s, 16, 0, 0);
}

// C = A(MxK, bf16, K-contig) * B^T (B given as N x K, bf16, K-contig)
// mode 0: write bf16 KQK2 (ldc=3072) with per-segment activation+bias
// mode 1: write fp32 out (ldc=N) with bias b0
__global__ __launch_bounds__(256) void gemm_bt(
        const unsigned short* __restrict__ A, const unsigned short* __restrict__ Bm,
        unsigned short* __restrict__ Cb, float* __restrict__ Cf,
        const float* __restrict__ b0, const float* __restrict__ b1, const float* __restrict__ b2,
        int K, int N, int mode) {
    __shared__ __align__(16) short As[128 * 32];   // 8 KB
    __shared__ __align__(16) short Bs[128 * 32];   // 8 KB
    int tid = threadIdx.x;
    int wid = tid >> 6, lane = tid & 63;
    int bm = blockIdx.x, bn = blockIdx.y;
    int wr = wid >> 1, wc = wid & 1;
    int lr = lane & 15, kg = lane >> 4;

    f32x4 acc[4][4];
#pragma unroll
    for (int i = 0; i < 4; ++i)
#pragma unroll
        for (int j = 0; j < 4; ++j) acc[i][j] = (f32x4){0.f, 0.f, 0.f, 0.f};

    const size_t rowA0 = (size_t)bm * 128;
    const size_t rowB0 = (size_t)bn * 128;
    int nk = K >> 5;
    for (int kt = 0; kt < nk; ++kt) {
        // stage A & B tiles (128x32 bf16 each) via async global->LDS, 16B/lane
#pragma unroll
        for (int p = 0; p < 2; ++p) {
            int qq = p * 256 + tid;
            int r  = qq >> 2;
            int cc = (qq & 3) << 3;
            gld_lds16(A  + (rowA0 + r) * K + kt * 32 + cc, (void*)(As + p * 2048 + wid * 512));
            gld_lds16(Bm + (rowB0 + r) * K + kt * 32 + cc, (void*)(Bs + p * 2048 + wid * 512));
        }
        __syncthreads();
        bf16x8 af[4], bff[4];
#pragma unroll
        for (int f = 0; f < 4; ++f) {
            af[f]  = *reinterpret_cast<const bf16x8*>(&As[(wr * 64 + f * 16 + lr) * 32 + kg * 8]);
            bff[f] = *reinterpret_cast<const bf16x8*>(&Bs[(wc * 64 + f * 16 + lr) * 32 + kg * 8]);
        }
#pragma unroll
        for (int fm = 0; fm < 4; ++fm)
#pragma unroll
            for (int fn = 0; fn < 4; ++fn)
                acc[fm][fn] = __builtin_amdgcn_mfma_f32_16x16x32_bf16(af[fm], bff[fn], acc[fm][fn], 0, 0, 0);
        __syncthreads();
    }

    int colBase = bn * 128 + wc * 64;
    int rowBase = bm * 128 + wr * 64;
    if (mode == 0) {
        int seg = bn >> 3;  // 1024-wide segments: 0=K1(exp) 1=Q1(sigmoid) 2=K2(ma_k)
        const float* bs = (seg == 0) ? b0 : ((seg == 1) ? b1 : b2);
#pragma unroll
        for (int fn = 0; fn < 4; ++fn) {
            int col = colBase + fn * 16 + lr;
            float bias = bs[col & 1023];
#pragma unroll
            for (int fm = 0; fm < 4; ++fm) {
#pragma unroll
                for (int j = 0; j < 4; ++j) {
                    int row = rowBase + fm * 16 + kg * 4 + j;
                    float v = acc[fm][fn][j] + bias;
                    float rv = (seg == 0) ? __expf(v)
                             : (seg == 1) ? sigmoidf_(v)
                                          : sigmoidf_(v * 6.25e-4f);
                    Cb[(size_t)row * 3072 + col] = f2bf(rv);
                }
            }
        }
    } else {
#pragma unroll
        for (int fn = 0; fn < 4; ++fn) {
            int col = colBase + fn * 16 + lr;
            float bias = b0[col];
#pragma unroll
            for (int fm = 0; fm < 4; ++fm) {
#pragma unroll
                for (int j = 0; j < 4; ++j) {
                    int row = rowBase + fm * 16 + kg * 4 + j;
                    Cf[(size_t)row * N + col] = acc[fm][fn][j] + bias;
                }
            }
        }
    }
}

// ---- chunked scan, pass 1: per-(b,chunk,d) partial sums of K and K*V ----
__global__ void pass1(const unsigned short* __restrict__ KQ, const float* __restrict__ x,
                      float* __restrict__ pK, float* __restrict__ pKV) {
    int tid = blockIdx.x * 256 + threadIdx.x;   // (b*CHUNKS + c)*1024 + d
    int d  = tid & 1023;
    int bc = tid >> 10;
    size_t row0 = ((size_t)(bc >> 6)) * L_DIM + (size_t)(bc & 63) * LC;
    const unsigned short* kp = KQ + row0 * 3072 + d;
    const float* vp = x + row0 * 1024 + d;
    float sK = 0.f, sKV = 0.f;
#pragma unroll 8
    for (int i = 0; i < LC; ++i) {
        float k = bf2f(kp[(size_t)i * 3072]);
        float v = vp[(size_t)i * 1024];
        sK += k;
        sKV += k * v;
    }
    pK[tid] = sK;
    pKV[tid] = sKV;
}

// exclusive scan over chunks (per (b,d) channel), in place, 2 arrays
__global__ void scan_ex2(float* __restrict__ pK, float* __restrict__ pKV) {
    int tid = blockIdx.x * 256 + threadIdx.x;   // 4096 threads
    int d = tid & 1023, b = tid >> 10;
    float rK = 0.f, rKV = 0.f;
#pragma unroll 8
    for (int c = 0; c < CHUNKS; ++c) {
        size_t i = ((size_t)(b * CHUNKS + c)) * 1024 + d;
        float a = pK[i], q = pKV[i];
        pK[i] = rK; pKV[i] = rKV;
        rK += a; rKV += q;
    }
}

__global__ void scan_ex1(float* __restrict__ p) {
    int tid = blockIdx.x * 256 + threadIdx.x;
    int d = tid & 1023, b = tid >> 10;
    float r = 0.f;
#pragma unroll 8
    for (int c = 0; c < CHUNKS; ++c) {
        size_t i = ((size_t)(b * CHUNKS + c)) * 1024 + d;
        float a = p[i]; p[i] = r; r += a;
    }
}

// ---- pass 3: finish AR branch, emit oar + m = K2[t-1]*(V[t]-oar[t-1]), chunk sums of m ----
__global__ void pass3(const unsigned short* __restrict__ KQ, const float* __restrict__ x,
                      const float* __restrict__ oK, const float* __restrict__ oKV,
                      unsigned short* __restrict__ oarB, unsigned short* __restrict__ mB,
                      float* __restrict__ pM) {
    int tid = blockIdx.x * 256 + threadIdx.x;
    int d  = tid & 1023;
    int bc = tid >> 10;
    int c  = bc & 63;
    size_t row0 = ((size_t)(bc >> 6)) * L_DIM + (size_t)c * LC;
    const unsigned short* kqp = KQ + row0 * 3072 + d;
    const float* vp = x + row0 * 1024 + d;
    float cK = oK[tid], cKV = oKV[tid];
    float oar_prev = 0.f;
    if (c != 0) {
        float qm1 = bf2f(kqp[-2048]);            // Q at row0-1: -3072 + 1024
        oar_prev = qm1 * (cKV / (cK + 1e-6f));
    }
    float sM = 0.f;
    // i = 0
    {
        float k = bf2f(kqp[0]);
        float q = bf2f(kqp[1024]);
        float v = vp[0];
        cK += k; cKV += k * v;
        float oar = q * (cKV / (cK + 1e-6f));
        float m = 0.f;
        if (c != 0) {
            float k2 = bf2f(kqp[-1024]);         // K2 at row0-1: -3072 + 2048
            m = k2 * (v - oar_prev);
        }
        sM += m;
        size_t gi = row0 * 1024 + d;
        oarB[gi] = f2bf(oar);
        mB[gi]   = f2bf(m);
        oar_prev = oar;
    }
#pragma unroll 4
    for (int i = 1; i < LC; ++i) {
        float k = bf2f(kqp[(size_t)i * 3072]);
        float q = bf2f(kqp[(size_t)i * 3072 + 1024]);
        float v = vp[(size_t)i * 1024];
        cK += k; cKV += k * v;
        float oar = q * (cKV / (cK + 1e-6f));
        float k2 = bf2f(kqp[(size_t)(i - 1) * 3072 + 2048]);   // K2 at row t-1
        float m = k2 * (v - oar_prev);
        sM += m;
        size_t gi = (row0 + (size_t)i) * 1024 + d;
        oarB[gi] = f2bf(oar);
        mB[gi]   = f2bf(m);
        oar_prev = oar;
    }
    pM[tid] = sM;
}

// ---- pass 5: finish MA branch, yin = oar + cumsum(m)*6.25e-4*Q[t-1] (bf16) ----
__global__ void pass5(const unsigned short* __restrict__ KQ,
                      const unsigned short* __restrict__ oarB, const unsigned short* __restrict__ mB,
                      const float* __restrict__ oM, unsigned short* __restrict__ yin) {
    int tid = blockIdx.x * 256 + threadIdx.x;
    int d  = tid & 1023;
    int bc = tid >> 10;
    int c  = bc & 63;
    size_t row0 = ((size_t)(bc >> 6)) * L_DIM + (size_t)c * LC;
    const unsigned short* qp = KQ + row0 * 3072 + 1024 + d;
    float cM = oM[tid];
    // i = 0
    {
        size_t gi = row0 * 1024 + d;
        cM += bf2f(mB[gi]);
        float qm1 = (c == 0) ? 0.f : bf2f(qp[-3072]);
        yin[gi] = f2bf(bf2f(oarB[gi]) + cM * 6.25e-4f * qm1);
    }
#pragma unroll 4
    for (int i = 1; i < LC; ++i) {
        size_t gi = (row0 + (size_t)i) * 1024 + d;
        cM += bf2f(mB[gi]);
        float qm1 = bf2f(qp[(size_t)(i - 1) * 3072]);
        yin[gi] = f2bf(bf2f(oarB[gi]) + cM * 6.25e-4f * qm1);
    }
}

extern "C" void kernel_launch(void* const* d_in, const int* in_sizes, int n_in,
                              void* d_out, int out_size, void* d_ws, size_t ws_size,
                              hipStream_t stream) {
    (void)in_sizes; (void)n_in; (void)out_size; (void)ws_size;
    const float* x   = (const float*)d_in[0];
    const float* Wq1 = (const float*)d_in[1];
    const float* bq1 = (const float*)d_in[2];
    const float* Wk1 = (const float*)d_in[3];
    const float* bk1 = (const float*)d_in[4];
    const float* Wk2 = (const float*)d_in[5];
    const float* bk2 = (const float*)d_in[6];
    const float* Wpj = (const float*)d_in[7];
    const float* bpj = (const float*)d_in[8];
    float* out = (float*)d_out;

    char* ws = (char*)d_ws;
    unsigned short* xbf   = (unsigned short*)(ws);                  // 33,554,432 B
    unsigned short* Wcat  = (unsigned short*)(ws + 33554432);       //  6,291,456 B
    unsigned short* Wpjbf = (unsigned short*)(ws + 39845888);       //  2,097,152 B
    unsigned short* KQ    = (unsigned short*)(ws + 41943040);       // 100,663,296 B (M x 3072 bf16)
    unsigned short* oarB  = (unsigned short*)(ws + 142606336);      // 33,554,432 B
    unsigned short* mB    = (unsigned short*)(ws + 176160768);      // 33,554,432 B
    unsigned short* yin   = (unsigned short*)(ws + 209715200);      // 33,554,432 B
    float* pK  = (float*)(ws + 243269632);                          // 1,048,576 B
    float* pKV = (float*)(ws + 244318208);                          // 1,048,576 B
    float* pM  = (float*)(ws + 245366784);                          // 1,048,576 B
    // total ~235 MiB

    const int nx = M_DIM * D_DIM;
    const int nw = D_DIM * D_DIM;
    cvt_bf16_kernel<<<nx / 4 / 256, 256, 0, stream>>>(x, xbf, nx);
    cvt_bf16_kernel<<<nw / 4 / 256, 256, 0, stream>>>(Wk1, Wcat, nw);
    cvt_bf16_kernel<<<nw / 4 / 256, 256, 0, stream>>>(Wq1, Wcat + nw, nw);
    cvt_bf16_kernel<<<nw / 4 / 256, 256, 0, stream>>>(Wk2, Wcat + 2 * nw, nw);
    cvt_bf16_kernel<<<nw / 4 / 256, 256, 0, stream>>>(Wpj, Wpjbf, nw);

    dim3 g1(M_DIM / 128, N1 / 128);
    gemm_bt<<<g1, 256, 0, stream>>>(xbf, Wcat, KQ, nullptr, bk1, bq1, bk2, D_DIM, N1, 0);

    pass1<<<M_DIM * D_DIM / LC / 256, 256, 0, stream>>>(KQ, x, pK, pKV);
    scan_ex2<<<16, 256, 0, stream>>>(pK, pKV);
    pass3<<<M_DIM * D_DIM / LC / 256, 256, 0, stream>>>(KQ, x, pK, pKV, oarB, mB, pM);
    scan_ex1<<<16, 256, 0, stream>>>(pM);
    pass5<<<M_DIM * D_DIM / LC / 256, 256, 0, stream>>>(KQ, oarB, mB, pM, yin);

    dim3 g2(M_DIM / 128, D_DIM / 128);
    gemm_bt<<<g2, 256, 0, stream>>>(yin, Wpjbf, nullptr, out, bpj, nullptr, nullptr, D_DIM, D_DIM, 1);
}

// Round 2
// 328.262 us; speedup vs baseline: 1.2121x; 1.2121x over previous
//
#include <hip/hip_runtime.h>

// Problem constants
#define D_DIM 1024
#define L_DIM 4096
#define B_DIM 4
#define M_DIM (B_DIM * L_DIM)   // 16384 rows
#define N1    3072              // concat of K1|Q1|K2 outputs
#define CHUNKS 64
#define LC     64               // chunk length (CHUNKS*LC == L_DIM)
#define KDIM  1024
#define NKT   16                // K tiles of 64

using f32x4  = __attribute__((ext_vector_type(4))) float;
using bf16x8 = __attribute__((ext_vector_type(8))) short;

__device__ __forceinline__ unsigned short f2bf(float f) {
    unsigned u = __float_as_uint(f);
    u += 0x7fffu + ((u >> 16) & 1u);   // RNE
    return (unsigned short)(u >> 16);
}
__device__ __forceinline__ float bf2f(unsigned short h) {
    return __uint_as_float(((unsigned)h) << 16);
}
__device__ __forceinline__ float sigmoidf_(float x) {
    return 1.0f / (1.0f + __expf(-x));
}

// fp32 -> bf16 conversion, 4 elems/thread
__global__ void cvt_bf16_kernel(const float* __restrict__ in, unsigned short* __restrict__ out, int n) {
    int i = (blockIdx.x * blockDim.x + threadIdx.x) * 4;
    if (i < n) {
        float4 v = *reinterpret_cast<const float4*>(in + i);
        uint2 p;
        p.x = (unsigned)f2bf(v.x) | ((unsigned)f2bf(v.y) << 16);
        p.y = (unsigned)f2bf(v.z) | ((unsigned)f2bf(v.w) << 16);
        *reinterpret_cast<uint2*>(out + i) = p;
    }
}

__device__ __forceinline__ void gld_lds16(const void* g, void* s) {
    __builtin_amdgcn_global_load_lds((const __attribute__((address_space(1))) void*)g,
                                     (__attribute__((address_space(3))) void*)s, 16, 0, 0);
}

#define BAR()  do { asm volatile("" ::: "memory"); __builtin_amdgcn_s_barrier(); asm volatile("" ::: "memory"); } while (0)
#define MFMA16(a_, b_, c_) __builtin_amdgcn_mfma_f32_16x16x32_bf16(a_, b_, c_, 0, 0, 0)

// ============================================================================
// 256x256 tile, BK=64, 8 waves (2M x 4N), 512 threads, 128 KiB LDS dbuf.
// 4 phases per K-tile (kh0/fn01, kh0/fn23, kh1/fn01, kh1/fn23), counted vmcnt.
// LDS layout (shorts): buf[2](32768) { A(16384){kh0(8192),kh1(8192)}, B(16384){...} }
// Within a (mat,kh) region: 256 rows x 4 slots of 16B; phys slot = row*4 + (slot ^ ((row>>1)&3)).
// ============================================================================
__global__ __launch_bounds__(512, 2) void gemm256(
        const unsigned short* __restrict__ A, const unsigned short* __restrict__ Bm,
        unsigned short* __restrict__ Cb, float* __restrict__ Cf,
        const float* __restrict__ bb0, const float* __restrict__ bb1, const float* __restrict__ bb2,
        int nwgDiv8, int mode) {
    extern __shared__ __align__(16) short lds[];
    const int tid  = threadIdx.x;
    const int wid  = tid >> 6, lane = tid & 63;
    const int wr   = wid >> 2, wc = wid & 3;      // 2M x 4N waves
    const int lr   = lane & 15, kg = lane >> 4;

    // T1: bijective XCD swizzle (gridX fixed = 64; nwg % 8 == 0)
    int lin = blockIdx.y * 64 + blockIdx.x;
    int swz = (lin & 7) * nwgDiv8 + (lin >> 3);
    int bm = swz & 63;
    int bn = swz >> 6;
    const size_t rowA0 = (size_t)bm * 256;
    const size_t rowB0 = (size_t)bn * 256;

    // staging geometry (T2 swizzle on SOURCE side; LDS dest is linear per lane)
    const int rh = tid >> 2;                       // row within 128-row half-call
    const int sl = (tid & 3) ^ ((rh >> 1) & 3);    // logical 16B slot to fetch
    const int wbase = (tid >> 6) * 512;            // wave's short offset in call region
    const size_t aoffG = (size_t)rh * KDIM + sl * 8;

#define STAGE(Mp_, row0_, kt_, kh_, c_, mat_, cur_) \
    gld_lds16((Mp_) + ((row0_) + (size_t)(c_) * 128) * KDIM + (size_t)(kt_) * 64 + (kh_) * 32 + aoffG, \
              (void*)(lds + (cur_) * 32768 + (mat_) * 16384 + (kh_) * 8192 + (c_) * 4096 + wbase))

    // read-side swizzled addresses (shorts)
    const int slotR = kg ^ ((lr >> 1) & 3);
    const int aRd = (wr * 128 + lr) * 32 + slotR * 8;   // + fm*512
    const int bRd = (wc * 64  + lr) * 32 + slotR * 8;   // + fn*512

    f32x4 acc[8][4];
#pragma unroll
    for (int i = 0; i < 8; ++i)
#pragma unroll
        for (int j = 0; j < 4; ++j) acc[i][j] = (f32x4){0.f, 0.f, 0.f, 0.f};

    // ---- prologue: tile0 all 4 halves, tile1 kh0 (12 calls); vmcnt(4) leaves tile1-kh0 in flight
    STAGE(A,  rowA0, 0, 0, 0, 0, 0); STAGE(A,  rowA0, 0, 0, 1, 0, 0);
    STAGE(Bm, rowB0, 0, 0, 0, 1, 0); STAGE(Bm, rowB0, 0, 0, 1, 1, 0);
    STAGE(A,  rowA0, 0, 1, 0, 0, 0); STAGE(A,  rowA0, 0, 1, 1, 0, 0);
    STAGE(Bm, rowB0, 0, 1, 0, 1, 0); STAGE(Bm, rowB0, 0, 1, 1, 1, 0);
    STAGE(A,  rowA0, 1, 0, 0, 0, 1); STAGE(A,  rowA0, 1, 0, 1, 0, 1);
    STAGE(Bm, rowB0, 1, 0, 0, 1, 1); STAGE(Bm, rowB0, 1, 0, 1, 1, 1);
    asm volatile("s_waitcnt vmcnt(4)" ::: "memory");
    BAR();

    for (int kt = 0; kt < NKT; ++kt) {
        const int cur = kt & 1;
        const short* A0 = lds + cur * 32768;
        const short* A1 = A0 + 8192;
        const short* B0 = A0 + 16384;
        const short* B1 = A0 + 24576;
        bf16x8 a[8], b0, b1, b2, b3;

        // ---- P1: kh0 x fn{0,1}; stage (kt+1, kh1) into other buffer
        #pragma unroll
        for (int fm = 0; fm < 8; ++fm) a[fm] = *reinterpret_cast<const bf16x8*>(A0 + aRd + fm * 512);
        b0 = *reinterpret_cast<const bf16x8*>(B0 + bRd);
        b1 = *reinterpret_cast<const bf16x8*>(B0 + bRd + 512);
        if (kt + 1 < NKT) {
            const int nc = cur ^ 1;
            STAGE(A,  rowA0, kt + 1, 1, 0, 0, nc); STAGE(A,  rowA0, kt + 1, 1, 1, 0, nc);
            STAGE(Bm, rowB0, kt + 1, 1, 0, 1, nc); STAGE(Bm, rowB0, kt + 1, 1, 1, 1, nc);
        }
        BAR();
        __builtin_amdgcn_s_setprio(1);
        #pragma unroll
        for (int fm = 0; fm < 8; ++fm) {
            acc[fm][0] = MFMA16(a[fm], b0, acc[fm][0]);
            acc[fm][1] = MFMA16(a[fm], b1, acc[fm][1]);
        }
        __builtin_amdgcn_s_setprio(0);
        BAR();

        // ---- P2: kh0 x fn{2,3}
        b2 = *reinterpret_cast<const bf16x8*>(B0 + bRd + 1024);
        b3 = *reinterpret_cast<const bf16x8*>(B0 + bRd + 1536);
        BAR();
        __builtin_amdgcn_s_setprio(1);
        #pragma unroll
        for (int fm = 0; fm < 8; ++fm) {
            acc[fm][2] = MFMA16(a[fm], b2, acc[fm][2]);
            acc[fm][3] = MFMA16(a[fm], b3, acc[fm][3]);
        }
        __builtin_amdgcn_s_setprio(0);
        BAR();

        // ---- P3: kh1 x fn{0,1}; stage (kt+2, kh0, A) into cur (kh0 dead after P2 barrier)
        #pragma unroll
        for (int fm = 0; fm < 8; ++fm) a[fm] = *reinterpret_cast<const bf16x8*>(A1 + aRd + fm * 512);
        b0 = *reinterpret_cast<const bf16x8*>(B1 + bRd);
        b1 = *reinterpret_cast<const bf16x8*>(B1 + bRd + 512);
        if (kt + 2 < NKT) {
            STAGE(A, rowA0, kt + 2, 0, 0, 0, cur); STAGE(A, rowA0, kt + 2, 0, 1, 0, cur);
        }
        BAR();
        __builtin_amdgcn_s_setprio(1);
        #pragma unroll
        for (int fm = 0; fm < 8; ++fm) {
            acc[fm][0] = MFMA16(a[fm], b0, acc[fm][0]);
            acc[fm][1] = MFMA16(a[fm], b1, acc[fm][1]);
        }
        __builtin_amdgcn_s_setprio(0);
        BAR();

        // ---- P4: kh1 x fn{2,3}; stage (kt+2, kh0, B); counted vmcnt at tile end
        b2 = *reinterpret_cast<const bf16x8*>(B1 + bRd + 1024);
        b3 = *reinterpret_cast<const bf16x8*>(B1 + bRd + 1536);
        if (kt + 2 < NKT) {
            STAGE(Bm, rowB0, kt + 2, 0, 0, 1, cur); STAGE(Bm, rowB0, kt + 2, 0, 1, 1, cur);
        }
        BAR();
        __builtin_amdgcn_s_setprio(1);
        #pragma unroll
        for (int fm = 0; fm < 8; ++fm) {
            acc[fm][2] = MFMA16(a[fm], b2, acc[fm][2]);
            acc[fm][3] = MFMA16(a[fm], b3, acc[fm][3]);
        }
        __builtin_amdgcn_s_setprio(0);
        if (kt < NKT - 2) { asm volatile("s_waitcnt vmcnt(4)" ::: "memory"); }
        else              { asm volatile("s_waitcnt vmcnt(0)" ::: "memory"); }
        BAR();
    }

    // ---- epilogue
    const int rowBase = bm * 256 + wr * 128;
    const int colBase = bn * 256 + wc * 64;
    if (mode == 0) {
        const int seg = (colBase >> 10);   // uniform per block (256-wide tile within 1024 segment)
        const float* bs = (seg == 0) ? bb0 : ((seg == 1) ? bb1 : bb2);
#pragma unroll
        for (int fn = 0; fn < 4; ++fn) {
            int col = colBase + fn * 16 + lr;
            float bias = bs[col & 1023];
#pragma unroll
            for (int fm = 0; fm < 8; ++fm) {
#pragma unroll
                for (int j = 0; j < 4; ++j) {
                    int row = rowBase + fm * 16 + kg * 4 + j;
                    float v = acc[fm][fn][j] + bias;
                    float rv = (seg == 0) ? __expf(v)
                             : (seg == 1) ? sigmoidf_(v)
                                          : sigmoidf_(v * 6.25e-4f);
                    Cb[(size_t)row * 3072 + col] = f2bf(rv);
                }
            }
        }
    } else {
#pragma unroll
        for (int fn = 0; fn < 4; ++fn) {
            int col = colBase + fn * 16 + lr;
            float bias = bb0[col];
#pragma unroll
            for (int fm = 0; fm < 8; ++fm) {
#pragma unroll
                for (int j = 0; j < 4; ++j) {
                    int row = rowBase + fm * 16 + kg * 4 + j;
                    Cf[(size_t)row * 1024 + col] = acc[fm][fn][j] + bias;
                }
            }
        }
    }
#undef STAGE
}

// ---- chunked scan, pass 1: per-(b,chunk,d) partial sums of K and K*V ----
__global__ void pass1(const unsigned short* __restrict__ KQ, const float* __restrict__ x,
                      float* __restrict__ pK, float* __restrict__ pKV) {
    int tid = blockIdx.x * 256 + threadIdx.x;   // (b*CHUNKS + c)*1024 + d
    int d  = tid & 1023;
    int bc = tid >> 10;
    size_t row0 = ((size_t)(bc >> 6)) * L_DIM + (size_t)(bc & 63) * LC;
    const unsigned short* kp = KQ + row0 * 3072 + d;
    const float* vp = x + row0 * 1024 + d;
    float sK = 0.f, sKV = 0.f;
#pragma unroll 8
    for (int i = 0; i < LC; ++i) {
        float k = bf2f(kp[(size_t)i * 3072]);
        float v = vp[(size_t)i * 1024];
        sK += k;
        sKV += k * v;
    }
    pK[tid] = sK;
    pKV[tid] = sKV;
}

// exclusive scan over chunks (per (b,d) channel), in place, 2 arrays
__global__ void scan_ex2(float* __restrict__ pK, float* __restrict__ pKV) {
    int tid = blockIdx.x * 256 + threadIdx.x;   // 4096 threads
    int d = tid & 1023, b = tid >> 10;
    float rK = 0.f, rKV = 0.f;
#pragma unroll 8
    for (int c = 0; c < CHUNKS; ++c) {
        size_t i = ((size_t)(b * CHUNKS + c)) * 1024 + d;
        float a = pK[i], q = pKV[i];
        pK[i] = rK; pKV[i] = rKV;
        rK += a; rKV += q;
    }
}

__global__ void scan_ex1(float* __restrict__ p) {
    int tid = blockIdx.x * 256 + threadIdx.x;
    int d = tid & 1023, b = tid >> 10;
    float r = 0.f;
#pragma unroll 8
    for (int c = 0; c < CHUNKS; ++c) {
        size_t i = ((size_t)(b * CHUNKS + c)) * 1024 + d;
        float a = p[i]; p[i] = r; r += a;
    }
}

// ---- pass 3: finish AR branch, emit oar + m = K2[t-1]*(V[t]-oar[t-1]), chunk sums of m ----
__global__ void pass3(const unsigned short* __restrict__ KQ, const float* __restrict__ x,
                      const float* __restrict__ oK, const float* __restrict__ oKV,
                      unsigned short* __restrict__ oarB, unsigned short* __restrict__ mB,
                      float* __restrict__ pM) {
    int tid = blockIdx.x * 256 + threadIdx.x;
    int d  = tid & 1023;
    int bc = tid >> 10;
    int c  = bc & 63;
    size_t row0 = ((size_t)(bc >> 6)) * L_DIM + (size_t)c * LC;
    const unsigned short* kqp = KQ + row0 * 3072 + d;
    const float* vp = x + row0 * 1024 + d;
    float cK = oK[tid], cKV = oKV[tid];
    float oar_prev = 0.f;
    if (c != 0) {
        float qm1 = bf2f(kqp[-2048]);            // Q at row0-1: -3072 + 1024
        oar_prev = qm1 * (cKV / (cK + 1e-6f));
    }
    float sM = 0.f;
    // i = 0
    {
        float k = bf2f(kqp[0]);
        float q = bf2f(kqp[1024]);
        float v = vp[0];
        cK += k; cKV += k * v;
        float oar = q * (cKV / (cK + 1e-6f));
        float m = 0.f;
        if (c != 0) {
            float k2 = bf2f(kqp[-1024]);         // K2 at row0-1: -3072 + 2048
            m = k2 * (v - oar_prev);
        }
        sM += m;
        size_t gi = row0 * 1024 + d;
        oarB[gi] = f2bf(oar);
        mB[gi]   = f2bf(m);
        oar_prev = oar;
    }
#pragma unroll 4
    for (int i = 1; i < LC; ++i) {
        float k = bf2f(kqp[(size_t)i * 3072]);
        float q = bf2f(kqp[(size_t)i * 3072 + 1024]);
        float v = vp[(size_t)i * 1024];
        cK += k; cKV += k * v;
        float oar = q * (cKV / (cK + 1e-6f));
        float k2 = bf2f(kqp[(size_t)(i - 1) * 3072 + 2048]);   // K2 at row t-1
        float m = k2 * (v - oar_prev);
        sM += m;
        size_t gi = (row0 + (size_t)i) * 1024 + d;
        oarB[gi] = f2bf(oar);
        mB[gi]   = f2bf(m);
        oar_prev = oar;
    }
    pM[tid] = sM;
}

// ---- pass 5: finish MA branch, yin = oar + cumsum(m)*6.25e-4*Q[t-1] (bf16) ----
__global__ void pass5(const unsigned short* __restrict__ KQ,
                      const unsigned short* __restrict__ oarB, const unsigned short* __restrict__ mB,
                      const float* __restrict__ oM, unsigned short* __restrict__ yin) {
    int tid = blockIdx.x * 256 + threadIdx.x;
    int d  = tid & 1023;
    int bc = tid >> 10;
    int c  = bc & 63;
    size_t row0 = ((size_t)(bc >> 6)) * L_DIM + (size_t)c * LC;
    const unsigned short* qp = KQ + row0 * 3072 + 1024 + d;
    float cM = oM[tid];
    // i = 0
    {
        size_t gi = row0 * 1024 + d;
        cM += bf2f(mB[gi]);
        float qm1 = (c == 0) ? 0.f : bf2f(qp[-3072]);
        yin[gi] = f2bf(bf2f(oarB[gi]) + cM * 6.25e-4f * qm1);
    }
#pragma unroll 4
    for (int i = 1; i < LC; ++i) {
        size_t gi = (row0 + (size_t)i) * 1024 + d;
        cM += bf2f(mB[gi]);
        float qm1 = bf2f(qp[(size_t)(i - 1) * 3072]);
        yin[gi] = f2bf(bf2f(oarB[gi]) + cM * 6.25e-4f * qm1);
    }
}

extern "C" void kernel_launch(void* const* d_in, const int* in_sizes, int n_in,
                              void* d_out, int out_size, void* d_ws, size_t ws_size,
                              hipStream_t stream) {
    (void)in_sizes; (void)n_in; (void)out_size; (void)ws_size;
    const float* x   = (const float*)d_in[0];
    const float* Wq1 = (const float*)d_in[1];
    const float* bq1 = (const float*)d_in[2];
    const float* Wk1 = (const float*)d_in[3];
    const float* bk1 = (const float*)d_in[4];
    const float* Wk2 = (const float*)d_in[5];
    const float* bk2 = (const float*)d_in[6];
    const float* Wpj = (const float*)d_in[7];
    const float* bpj = (const float*)d_in[8];
    float* out = (float*)d_out;

    char* ws = (char*)d_ws;
    unsigned short* xbf   = (unsigned short*)(ws);                  // 33,554,432 B
    unsigned short* Wcat  = (unsigned short*)(ws + 33554432);       //  6,291,456 B
    unsigned short* Wpjbf = (unsigned short*)(ws + 39845888);       //  2,097,152 B
    unsigned short* KQ    = (unsigned short*)(ws + 41943040);       // 100,663,296 B (M x 3072 bf16)
    unsigned short* oarB  = (unsigned short*)(ws + 142606336);      // 33,554,432 B
    unsigned short* mB    = (unsigned short*)(ws + 176160768);      // 33,554,432 B
    unsigned short* yin   = (unsigned short*)(ws + 209715200);      // 33,554,432 B
    float* pK  = (float*)(ws + 243269632);                          // 1,048,576 B
    float* pKV = (float*)(ws + 244318208);                          // 1,048,576 B
    float* pM  = (float*)(ws + 245366784);                          // 1,048,576 B

    // allow 128 KiB dynamic LDS (idempotent host-side config; not a stream op)
    (void)hipFuncSetAttribute((const void*)gemm256,
                              hipFuncAttributeMaxDynamicSharedMemorySize, 131072);

    const int nx = M_DIM * D_DIM;
    const int nw = D_DIM * D_DIM;
    cvt_bf16_kernel<<<nx / 4 / 256, 256, 0, stream>>>(x, xbf, nx);
    cvt_bf16_kernel<<<nw / 4 / 256, 256, 0, stream>>>(Wk1, Wcat, nw);
    cvt_bf16_kernel<<<nw / 4 / 256, 256, 0, stream>>>(Wq1, Wcat + nw, nw);
    cvt_bf16_kernel<<<nw / 4 / 256, 256, 0, stream>>>(Wk2, Wcat + 2 * nw, nw);
    cvt_bf16_kernel<<<nw / 4 / 256, 256, 0, stream>>>(Wpj, Wpjbf, nw);

    // GEMM1: 16384 x 3072 x 1024, bf16 out with activations
    gemm256<<<dim3(64, 12), 512, 131072, stream>>>(xbf, Wcat, KQ, nullptr,
                                                   bk1, bq1, bk2, 96, 0);

    pass1<<<M_DIM * D_DIM / LC / 256, 256, 0, stream>>>(KQ, x, pK, pKV);
    scan_ex2<<<16, 256, 0, stream>>>(pK, pKV);
    pass3<<<M_DIM * D_DIM / LC / 256, 256, 0, stream>>>(KQ, x, pK, pKV, oarB, mB, pM);
    scan_ex1<<<16, 256, 0, stream>>>(pM);
    pass5<<<M_DIM * D_DIM / LC / 256, 256, 0, stream>>>(KQ, oarB, mB, pM, yin);

    // GEMM2: 16384 x 1024 x 1024, fp32 out with bias
    gemm256<<<dim3(64, 4), 512, 131072, stream>>>(yin, Wpjbf, nullptr, out,
                                                  bpj, nullptr, nullptr, 32, 1);
}

// Round 3
// 315.872 us; speedup vs baseline: 1.2596x; 1.0392x over previous
//
#include <hip/hip_runtime.h>

// Problem constants
#define D_DIM 1024
#define L_DIM 4096
#define B_DIM 4
#define M_DIM (B_DIM * L_DIM)   // 16384 rows
#define N1    3072              // concat of K1|Q1|K2 outputs
#define CHUNKS 64
#define LC     64               // chunk length (CHUNKS*LC == L_DIM)
#define KDIM  1024
#define NKT   16                // K tiles of 64

using f32x4  = __attribute__((ext_vector_type(4))) float;
using bf16x8 = __attribute__((ext_vector_type(8))) short;

__device__ __forceinline__ unsigned short f2bf(float f) {
    unsigned u = __float_as_uint(f);
    u += 0x7fffu + ((u >> 16) & 1u);   // RNE
    return (unsigned short)(u >> 16);
}
__device__ __forceinline__ float bf2f(unsigned short h) {
    return __uint_as_float(((unsigned)h) << 16);
}
__device__ __forceinline__ float sigmoidf_(float x) {
    return 1.0f / (1.0f + __expf(-x));
}

// fp32 -> bf16 conversion, 4 elems/thread
__global__ void cvt_bf16_kernel(const float* __restrict__ in, unsigned short* __restrict__ out, int n) {
    int i = (blockIdx.x * blockDim.x + threadIdx.x) * 4;
    if (i < n) {
        float4 v = *reinterpret_cast<const float4*>(in + i);
        uint2 p;
        p.x = (unsigned)f2bf(v.x) | ((unsigned)f2bf(v.y) << 16);
        p.y = (unsigned)f2bf(v.z) | ((unsigned)f2bf(v.w) << 16);
        *reinterpret_cast<uint2*>(out + i) = p;
    }
}

__device__ __forceinline__ void gld_lds16(const void* g, void* s) {
    __builtin_amdgcn_global_load_lds((const __attribute__((address_space(1))) void*)g,
                                     (__attribute__((address_space(3))) void*)s, 16, 0, 0);
}

#define BAR()  do { asm volatile("" ::: "memory"); __builtin_amdgcn_s_barrier(); asm volatile("" ::: "memory"); } while (0)
#define MFMA16(a_, b_, c_) __builtin_amdgcn_mfma_f32_16x16x32_bf16(a_, b_, c_, 0, 0, 0)

// ============================================================================
// 256x256 tile, BK=64, 8 waves (2M x 4N), 512 threads, 128 KiB LDS dbuf.
// 4 phases per K-tile, counted vmcnt (never 0 in steady state).
// OPERAND-SWAPPED MFMA: acc[fm][fn] = mfma(b_fn, a_fm, .) so each lane holds
//   C row = fm*16 + lr, C cols = fn*16 + kg*4 + j (4 CONSECUTIVE cols)
//   -> epilogue stores are 8B (bf16x4) / 16B (f32x4) contiguous per lane.
// LDS layout (shorts): buf[2](32768) { A(16384){kh0(8192),kh1(8192)}, B(16384){...} }
// Within a (mat,kh) region: 256 rows x 4 slots of 16B; phys slot = slot ^ ((row>>1)&3).
// ============================================================================
__global__ __launch_bounds__(512, 2) void gemm256(
        const unsigned short* __restrict__ A, const unsigned short* __restrict__ Bm,
        unsigned short* __restrict__ Cb, float* __restrict__ Cf,
        const float* __restrict__ bb0, const float* __restrict__ bb1, const float* __restrict__ bb2,
        int nwgDiv8, int mode) {
    extern __shared__ __align__(16) short lds[];
    const int tid  = threadIdx.x;
    const int wid  = tid >> 6, lane = tid & 63;
    const int wr   = wid >> 2, wc = wid & 3;      // 2M x 4N waves
    const int lr   = lane & 15, kg = lane >> 4;

    // T1: bijective XCD swizzle (gridX fixed = 64; nwg % 8 == 0)
    int lin = blockIdx.y * 64 + blockIdx.x;
    int swz = (lin & 7) * nwgDiv8 + (lin >> 3);
    int bm = swz & 63;
    int bn = swz >> 6;
    const size_t rowA0 = (size_t)bm * 256;
    const size_t rowB0 = (size_t)bn * 256;

    // staging geometry (T2 swizzle on SOURCE side; LDS dest is linear per lane)
    const int rh = tid >> 2;                       // row within 128-row half-call
    const int sl = (tid & 3) ^ ((rh >> 1) & 3);    // logical 16B slot to fetch
    const int wbase = (tid >> 6) * 512;            // wave's short offset in call region
    const size_t aoffG = (size_t)rh * KDIM + sl * 8;

#define STAGE(Mp_, row0_, kt_, kh_, c_, mat_, cur_) \
    gld_lds16((Mp_) + ((row0_) + (size_t)(c_) * 128) * KDIM + (size_t)(kt_) * 64 + (kh_) * 32 + aoffG, \
              (void*)(lds + (cur_) * 32768 + (mat_) * 16384 + (kh_) * 8192 + (c_) * 4096 + wbase))

    // read-side swizzled addresses (shorts)
    const int slotR = kg ^ ((lr >> 1) & 3);
    const int aRd = (wr * 128 + lr) * 32 + slotR * 8;   // + fm*512
    const int bRd = (wc * 64  + lr) * 32 + slotR * 8;   // + fn*512

    f32x4 acc[8][4];
#pragma unroll
    for (int i = 0; i < 8; ++i)
#pragma unroll
        for (int j = 0; j < 4; ++j) acc[i][j] = (f32x4){0.f, 0.f, 0.f, 0.f};

    // ---- prologue: tile0 all 4 halves, tile1 kh0 (12 calls); vmcnt(4) leaves tile1-kh0 in flight
    STAGE(A,  rowA0, 0, 0, 0, 0, 0); STAGE(A,  rowA0, 0, 0, 1, 0, 0);
    STAGE(Bm, rowB0, 0, 0, 0, 1, 0); STAGE(Bm, rowB0, 0, 0, 1, 1, 0);
    STAGE(A,  rowA0, 0, 1, 0, 0, 0); STAGE(A,  rowA0, 0, 1, 1, 0, 0);
    STAGE(Bm, rowB0, 0, 1, 0, 1, 0); STAGE(Bm, rowB0, 0, 1, 1, 1, 0);
    STAGE(A,  rowA0, 1, 0, 0, 0, 1); STAGE(A,  rowA0, 1, 0, 1, 0, 1);
    STAGE(Bm, rowB0, 1, 0, 0, 1, 1); STAGE(Bm, rowB0, 1, 0, 1, 1, 1);
    asm volatile("s_waitcnt vmcnt(4)" ::: "memory");
    BAR();

    for (int kt = 0; kt < NKT; ++kt) {
        const int cur = kt & 1;
        const short* A0 = lds + cur * 32768;
        const short* A1 = A0 + 8192;
        const short* B0 = A0 + 16384;
        const short* B1 = A0 + 24576;
        bf16x8 a[8], b0, b1, b2, b3;

        // ---- P1: kh0 x fn{0,1}; all kh0 reads issued here; stage (kt+1, kh1)
        #pragma unroll
        for (int fm = 0; fm < 8; ++fm) a[fm] = *reinterpret_cast<const bf16x8*>(A0 + aRd + fm * 512);
        b0 = *reinterpret_cast<const bf16x8*>(B0 + bRd);
        b1 = *reinterpret_cast<const bf16x8*>(B0 + bRd + 512);
        b2 = *reinterpret_cast<const bf16x8*>(B0 + bRd + 1024);
        b3 = *reinterpret_cast<const bf16x8*>(B0 + bRd + 1536);
        if (kt + 1 < NKT) {
            const int nc = cur ^ 1;
            STAGE(A,  rowA0, kt + 1, 1, 0, 0, nc); STAGE(A,  rowA0, kt + 1, 1, 1, 0, nc);
            STAGE(Bm, rowB0, kt + 1, 1, 0, 1, nc); STAGE(Bm, rowB0, kt + 1, 1, 1, 1, nc);
        }
        BAR();
        __builtin_amdgcn_s_setprio(1);
        #pragma unroll
        for (int fm = 0; fm < 8; ++fm) {
            acc[fm][0] = MFMA16(b0, a[fm], acc[fm][0]);
            acc[fm][1] = MFMA16(b1, a[fm], acc[fm][1]);
        }
        __builtin_amdgcn_s_setprio(0);
        BAR();

        // ---- P2: kh0 x fn{2,3}
        BAR();
        __builtin_amdgcn_s_setprio(1);
        #pragma unroll
        for (int fm = 0; fm < 8; ++fm) {
            acc[fm][2] = MFMA16(b2, a[fm], acc[fm][2]);
            acc[fm][3] = MFMA16(b3, a[fm], acc[fm][3]);
        }
        __builtin_amdgcn_s_setprio(0);
        BAR();

        // ---- P3: kh1 x fn{0,1}; all kh1 reads; stage (kt+2, kh0, A) into cur
        #pragma unroll
        for (int fm = 0; fm < 8; ++fm) a[fm] = *reinterpret_cast<const bf16x8*>(A1 + aRd + fm * 512);
        b0 = *reinterpret_cast<const bf16x8*>(B1 + bRd);
        b1 = *reinterpret_cast<const bf16x8*>(B1 + bRd + 512);
        b2 = *reinterpret_cast<const bf16x8*>(B1 + bRd + 1024);
        b3 = *reinterpret_cast<const bf16x8*>(B1 + bRd + 1536);
        if (kt + 2 < NKT) {
            STAGE(A, rowA0, kt + 2, 0, 0, 0, cur); STAGE(A, rowA0, kt + 2, 0, 1, 0, cur);
        }
        BAR();
        __builtin_amdgcn_s_setprio(1);
        #pragma unroll
        for (int fm = 0; fm < 8; ++fm) {
            acc[fm][0] = MFMA16(b0, a[fm], acc[fm][0]);
            acc[fm][1] = MFMA16(b1, a[fm], acc[fm][1]);
        }
        __builtin_amdgcn_s_setprio(0);
        BAR();

        // ---- P4: kh1 x fn{2,3}; stage (kt+2, kh0, B); counted vmcnt at tile end
        if (kt + 2 < NKT) {
            STAGE(Bm, rowB0, kt + 2, 0, 0, 1, cur); STAGE(Bm, rowB0, kt + 2, 0, 1, 1, cur);
        }
        BAR();
        __builtin_amdgcn_s_setprio(1);
        #pragma unroll
        for (int fm = 0; fm < 8; ++fm) {
            acc[fm][2] = MFMA16(b2, a[fm], acc[fm][2]);
            acc[fm][3] = MFMA16(b3, a[fm], acc[fm][3]);
        }
        __builtin_amdgcn_s_setprio(0);
        if (kt < NKT - 2) { asm volatile("s_waitcnt vmcnt(4)" ::: "memory"); }
        else              { asm volatile("s_waitcnt vmcnt(0)" ::: "memory"); }
        BAR();
    }

    // ---- epilogue (swapped layout: lane holds C row = fm*16+lr, cols = fn*16+kg*4+j)
    const int rowBase = bm * 256 + wr * 128;
    const int colBase = bn * 256 + wc * 64;
    if (mode == 0) {
        const int seg = (colBase >> 10);   // uniform per block
        const float* bs = (seg == 0) ? bb0 : ((seg == 1) ? bb1 : bb2);
#pragma unroll
        for (int fm = 0; fm < 8; ++fm) {
            int row = rowBase + fm * 16 + lr;
            unsigned short* cp = Cb + (size_t)row * 3072;
#pragma unroll
            for (int fn = 0; fn < 4; ++fn) {
                int col0 = colBase + fn * 16 + kg * 4;
                float4 b4 = *reinterpret_cast<const float4*>(bs + (col0 & 1023));
                float v0 = acc[fm][fn][0] + b4.x;
                float v1 = acc[fm][fn][1] + b4.y;
                float v2 = acc[fm][fn][2] + b4.z;
                float v3 = acc[fm][fn][3] + b4.w;
                float r0, r1, r2, r3;
                if (seg == 0)      { r0 = __expf(v0); r1 = __expf(v1); r2 = __expf(v2); r3 = __expf(v3); }
                else if (seg == 1) { r0 = sigmoidf_(v0); r1 = sigmoidf_(v1); r2 = sigmoidf_(v2); r3 = sigmoidf_(v3); }
                else               { r0 = sigmoidf_(v0 * 6.25e-4f); r1 = sigmoidf_(v1 * 6.25e-4f);
                                     r2 = sigmoidf_(v2 * 6.25e-4f); r3 = sigmoidf_(v3 * 6.25e-4f); }
                uint2 p;
                p.x = (unsigned)f2bf(r0) | ((unsigned)f2bf(r1) << 16);
                p.y = (unsigned)f2bf(r2) | ((unsigned)f2bf(r3) << 16);
                *reinterpret_cast<uint2*>(cp + col0) = p;
            }
        }
    } else {
#pragma unroll
        for (int fm = 0; fm < 8; ++fm) {
            int row = rowBase + fm * 16 + lr;
            float* cp = Cf + (size_t)row * 1024;
#pragma unroll
            for (int fn = 0; fn < 4; ++fn) {
                int col0 = colBase + fn * 16 + kg * 4;
                float4 b4 = *reinterpret_cast<const float4*>(bb0 + col0);
                float4 v;
                v.x = acc[fm][fn][0] + b4.x;
                v.y = acc[fm][fn][1] + b4.y;
                v.z = acc[fm][fn][2] + b4.z;
                v.w = acc[fm][fn][3] + b4.w;
                *reinterpret_cast<float4*>(cp + col0) = v;
            }
        }
    }
#undef STAGE
}

// ---- chunked scan, pass 1: per-(b,chunk,d) partial sums of K and K*V ----
__global__ void pass1(const unsigned short* __restrict__ KQ, const float* __restrict__ x,
                      float* __restrict__ pK, float* __restrict__ pKV) {
    int tid = blockIdx.x * 256 + threadIdx.x;   // (b*CHUNKS + c)*1024 + d
    int d  = tid & 1023;
    int bc = tid >> 10;
    size_t row0 = ((size_t)(bc >> 6)) * L_DIM + (size_t)(bc & 63) * LC;
    const unsigned short* kp = KQ + row0 * 3072 + d;
    const float* vp = x + row0 * 1024 + d;
    float sK = 0.f, sKV = 0.f;
#pragma unroll 8
    for (int i = 0; i < LC; ++i) {
        float k = bf2f(kp[(size_t)i * 3072]);
        float v = vp[(size_t)i * 1024];
        sK += k;
        sKV += k * v;
    }
    pK[tid] = sK;
    pKV[tid] = sKV;
}

// exclusive scan over chunks (per (b,d) channel), in place, 2 arrays
__global__ void scan_ex2(float* __restrict__ pK, float* __restrict__ pKV) {
    int tid = blockIdx.x * 256 + threadIdx.x;   // 4096 threads
    int d = tid & 1023, b = tid >> 10;
    float rK = 0.f, rKV = 0.f;
#pragma unroll 8
    for (int c = 0; c < CHUNKS; ++c) {
        size_t i = ((size_t)(b * CHUNKS + c)) * 1024 + d;
        float a = pK[i], q = pKV[i];
        pK[i] = rK; pKV[i] = rKV;
        rK += a; rKV += q;
    }
}

__global__ void scan_ex1(float* __restrict__ p) {
    int tid = blockIdx.x * 256 + threadIdx.x;
    int d = tid & 1023, b = tid >> 10;
    float r = 0.f;
#pragma unroll 8
    for (int c = 0; c < CHUNKS; ++c) {
        size_t i = ((size_t)(b * CHUNKS + c)) * 1024 + d;
        float a = p[i]; p[i] = r; r += a;
    }
}

// ---- pass 3: finish AR branch, emit oar + m = K2[t-1]*(V[t]-oar[t-1]), chunk sums of m ----
__global__ void pass3(const unsigned short* __restrict__ KQ, const float* __restrict__ x,
                      const float* __restrict__ oK, const float* __restrict__ oKV,
                      unsigned short* __restrict__ oarB, unsigned short* __restrict__ mB,
                      float* __restrict__ pM) {
    int tid = blockIdx.x * 256 + threadIdx.x;
    int d  = tid & 1023;
    int bc = tid >> 10;
    int c  = bc & 63;
    size_t row0 = ((size_t)(bc >> 6)) * L_DIM + (size_t)c * LC;
    const unsigned short* kqp = KQ + row0 * 3072 + d;
    const float* vp = x + row0 * 1024 + d;
    float cK = oK[tid], cKV = oKV[tid];
    float oar_prev = 0.f;
    if (c != 0) {
        float qm1 = bf2f(kqp[-2048]);            // Q at row0-1: -3072 + 1024
        oar_prev = qm1 * (cKV / (cK + 1e-6f));
    }
    float sM = 0.f;
    // i = 0
    {
        float k = bf2f(kqp[0]);
        float q = bf2f(kqp[1024]);
        float v = vp[0];
        cK += k; cKV += k * v;
        float oar = q * (cKV / (cK + 1e-6f));
        float m = 0.f;
        if (c != 0) {
            float k2 = bf2f(kqp[-1024]);         // K2 at row0-1: -3072 + 2048
            m = k2 * (v - oar_prev);
        }
        sM += m;
        size_t gi = row0 * 1024 + d;
        oarB[gi] = f2bf(oar);
        mB[gi]   = f2bf(m);
        oar_prev = oar;
    }
#pragma unroll 4
    for (int i = 1; i < LC; ++i) {
        float k = bf2f(kqp[(size_t)i * 3072]);
        float q = bf2f(kqp[(size_t)i * 3072 + 1024]);
        float v = vp[(size_t)i * 1024];
        cK += k; cKV += k * v;
        float oar = q * (cKV / (cK + 1e-6f));
        float k2 = bf2f(kqp[(size_t)(i - 1) * 3072 + 2048]);   // K2 at row t-1
        float m = k2 * (v - oar_prev);
        sM += m;
        size_t gi = (row0 + (size_t)i) * 1024 + d;
        oarB[gi] = f2bf(oar);
        mB[gi]   = f2bf(m);
        oar_prev = oar;
    }
    pM[tid] = sM;
}

// ---- pass 5: finish MA branch, yin = oar + cumsum(m)*6.25e-4*Q[t-1] (bf16) ----
__global__ void pass5(const unsigned short* __restrict__ KQ,
                      const unsigned short* __restrict__ oarB, const unsigned short* __restrict__ mB,
                      const float* __restrict__ oM, unsigned short* __restrict__ yin) {
    int tid = blockIdx.x * 256 + threadIdx.x;
    int d  = tid & 1023;
    int bc = tid >> 10;
    int c  = bc & 63;
    size_t row0 = ((size_t)(bc >> 6)) * L_DIM + (size_t)c * LC;
    const unsigned short* qp = KQ + row0 * 3072 + 1024 + d;
    float cM = oM[tid];
    // i = 0
    {
        size_t gi = row0 * 1024 + d;
        cM += bf2f(mB[gi]);
        float qm1 = (c == 0) ? 0.f : bf2f(qp[-3072]);
        yin[gi] = f2bf(bf2f(oarB[gi]) + cM * 6.25e-4f * qm1);
    }
#pragma unroll 4
    for (int i = 1; i < LC; ++i) {
        size_t gi = (row0 + (size_t)i) * 1024 + d;
        cM += bf2f(mB[gi]);
        float qm1 = bf2f(qp[(size_t)(i - 1) * 3072]);
        yin[gi] = f2bf(bf2f(oarB[gi]) + cM * 6.25e-4f * qm1);
    }
}

extern "C" void kernel_launch(void* const* d_in, const int* in_sizes, int n_in,
                              void* d_out, int out_size, void* d_ws, size_t ws_size,
                              hipStream_t stream) {
    (void)in_sizes; (void)n_in; (void)out_size; (void)ws_size;
    const float* x   = (const float*)d_in[0];
    const float* Wq1 = (const float*)d_in[1];
    const float* bq1 = (const float*)d_in[2];
    const float* Wk1 = (const float*)d_in[3];
    const float* bk1 = (const float*)d_in[4];
    const float* Wk2 = (const float*)d_in[5];
    const float* bk2 = (const float*)d_in[6];
    const float* Wpj = (const float*)d_in[7];
    const float* bpj = (const float*)d_in[8];
    float* out = (float*)d_out;

    char* ws = (char*)d_ws;
    unsigned short* xbf   = (unsigned short*)(ws);                  // 33,554,432 B
    unsigned short* Wcat  = (unsigned short*)(ws + 33554432);       //  6,291,456 B
    unsigned short* Wpjbf = (unsigned short*)(ws + 39845888);       //  2,097,152 B
    unsigned short* KQ    = (unsigned short*)(ws + 41943040);       // 100,663,296 B (M x 3072 bf16)
    unsigned short* oarB  = (unsigned short*)(ws + 142606336);      // 33,554,432 B
    unsigned short* mB    = (unsigned short*)(ws + 176160768);      // 33,554,432 B
    unsigned short* yin   = (unsigned short*)(ws + 209715200);      // 33,554,432 B
    float* pK  = (float*)(ws + 243269632);                          // 1,048,576 B
    float* pKV = (float*)(ws + 244318208);                          // 1,048,576 B
    float* pM  = (float*)(ws + 245366784);                          // 1,048,576 B

    (void)hipFuncSetAttribute((const void*)gemm256,
                              hipFuncAttributeMaxDynamicSharedMemorySize, 131072);

    const int nx = M_DIM * D_DIM;
    const int nw = D_DIM * D_DIM;
    cvt_bf16_kernel<<<nx / 4 / 256, 256, 0, stream>>>(x, xbf, nx);
    cvt_bf16_kernel<<<nw / 4 / 256, 256, 0, stream>>>(Wk1, Wcat, nw);
    cvt_bf16_kernel<<<nw / 4 / 256, 256, 0, stream>>>(Wq1, Wcat + nw, nw);
    cvt_bf16_kernel<<<nw / 4 / 256, 256, 0, stream>>>(Wk2, Wcat + 2 * nw, nw);
    cvt_bf16_kernel<<<nw / 4 / 256, 256, 0, stream>>>(Wpj, Wpjbf, nw);

    // GEMM1: 16384 x 3072 x 1024, bf16 out with activations
    gemm256<<<dim3(64, 12), 512, 131072, stream>>>(xbf, Wcat, KQ, nullptr,
                                                   bk1, bq1, bk2, 96, 0);

    pass1<<<M_DIM * D_DIM / LC / 256, 256, 0, stream>>>(KQ, x, pK, pKV);
    scan_ex2<<<16, 256, 0, stream>>>(pK, pKV);
    pass3<<<M_DIM * D_DIM / LC / 256, 256, 0, stream>>>(KQ, x, pK, pKV, oarB, mB, pM);
    scan_ex1<<<16, 256, 0, stream>>>(pM);
    pass5<<<M_DIM * D_DIM / LC / 256, 256, 0, stream>>>(KQ, oarB, mB, pM, yin);

    // GEMM2: 16384 x 1024 x 1024, fp32 out with bias
    gemm256<<<dim3(64, 4), 512, 131072, stream>>>(yin, Wpjbf, nullptr, out,
                                                  bpj, nullptr, nullptr, 32, 1);
}